// Round 13
// baseline (104.488 us; speedup 1.0000x reference)
//
#include <hip/hip_runtime.h>
#include <hip/hip_bf16.h>

#define NN 10000
#define NE 320000
#define IN_DIM 256
#define HID_DIM 512
#define OUT_DIM 256
#define CAP 96   // per-node edge bucket capacity; P(deg>96)~1e-15 for uniform 320k/10k

typedef __attribute__((ext_vector_type(8))) short sh8;
typedef __attribute__((ext_vector_type(4))) float f32x4;
typedef __attribute__((ext_vector_type(4))) ushort u16x4;

__device__ __forceinline__ ushort f2b(float f) {
    uint u = __builtin_bit_cast(uint, f);
    u = (u + 0x7FFFu + ((u >> 16) & 1u)) >> 16;
    return (ushort)u;
}
__device__ __forceinline__ float b2f(ushort h) {
    uint u = ((uint)h) << 16;
    return __builtin_bit_cast(float, u);
}

// async global->LDS, 16B per lane. LDS dest = wave-uniform base + lane*16 (HW rule).
__device__ __forceinline__ void g2l16(const ushort* g, ushort* l) {
    __builtin_amdgcn_global_load_lds(
        (const __attribute__((address_space(1))) void*)g,
        (__attribute__((address_space(3))) void*)l,
        16, 0, 0);
}

// fused prep: [0,2500) x->bf16 (4/thread); [2500,3012) W1t; [3012,3524) W2t;
// [3524,3564) zero cursor
__global__ void k_conv(const float* __restrict__ x, ushort* __restrict__ xb,
                       const float* __restrict__ W1, ushort* __restrict__ W1t,
                       const float* __restrict__ W2, ushort* __restrict__ W2t,
                       int* __restrict__ cursor) {
    const int b = blockIdx.x, t = threadIdx.x;
    if (b < 2500) {
        size_t i = ((size_t)b * 256 + t) * 4;
        float4 f = *(const float4*)&x[i];
        *(ushort4*)&xb[i] = make_ushort4(f2b(f.x), f2b(f.y), f2b(f.z), f2b(f.w));
    } else if (b < 3012) {
        int idx = (b - 2500) * 256 + t;          // n*256 + k
        int n = idx >> 8, k = idx & 255;
        W1t[idx] = f2b(W1[(size_t)k * HID_DIM + n]);
    } else if (b < 3524) {
        int idx = (b - 3012) * 256 + t;          // n*512 + k
        int n = idx >> 9, k = idx & 511;
        W2t[idx] = f2b(W2[(size_t)k * OUT_DIM + n]);
    } else {
        int idx = (b - 3524) * 256 + t;
        cursor[idx] = 0;                          // 40*256 = 10240 exactly
    }
}

// bucket fill, src index only; cursor ends up holding in-degree
__global__ void k_fill(const int* __restrict__ src, const int* __restrict__ dst,
                       int* cursor, int* __restrict__ edges, int e) {
    int i = blockIdx.x * blockDim.x + threadIdx.x;
    if (i < e) {
        int d = dst[i];
        int pos = atomicAdd(&cursor[d], 1);
        if (pos < CAP) edges[(size_t)d * CAP + pos] = src[i];
    }
}

// Pull aggregation, XCD-pinned dim-split (round-10) + NON-TEMPORAL streams:
// blockIdx%8 -> XCD; XCDs 0-3 do dims [0,128), 4-7 dims [128,256). Single-use
// streams (edge records, pert, output) are nontemporal so the per-XCD protected
// set is table-half 2.56 MB + cnt 40 KB < 4 MB L2 -> resident (round 10's null:
// the streams evicted the table; this removes them from LRU).
// One wave per node; quarter-wave (16 lanes x 16B) owns a quarter of the edges.
template <bool FINAL>
__global__ __launch_bounds__(256) void k_agg(const ushort* __restrict__ tbl,
                                             const int* __restrict__ cnt,
                                             const int* __restrict__ edges,
                                             const float* __restrict__ bias,
                                             const float* __restrict__ pert,
                                             void* __restrict__ outv) {
    const int t = threadIdx.x;
    const int b = blockIdx.x;
    const int g = b & 7;
    const int dimhalf = g >> 2;                       // XCD 0-3 -> 0, 4-7 -> 1
    const int nodeblk = (b >> 3) * 4 + (g & 3);       // [0, 2500)
    const int v = nodeblk * 4 + (t >> 6);             // wave -> node
    const int lane = t & 63;
    const int qtr = lane >> 4;                        // edge-quarter 0..3
    const int d0 = dimhalf * 128 + (lane & 15) * 8;   // 8 dims (16B) per lane
    const int deg = min(cnt[v], CAP);
    const float dv = rsqrtf((float)(deg + 1));
    const int base = (deg * qtr) >> 2;
    const int n = ((deg * (qtr + 1)) >> 2) - base;
    const int* ep = edges + (size_t)v * CAP + base;

    float a[8];
    if (qtr == 0) {
        sh8 hv = *(const sh8*)&tbl[(size_t)v * 256 + d0];
#pragma unroll
        for (int j = 0; j < 8; ++j) a[j] = b2f((ushort)hv[j]) * dv;
    } else {
#pragma unroll
        for (int j = 0; j < 8; ++j) a[j] = 0.f;
    }

    int i = 0;
    for (; i + 2 <= n; i += 2) {
        int s0 = __builtin_nontemporal_load(ep + i);
        int s1 = __builtin_nontemporal_load(ep + i + 1);
        float w0 = rsqrtf((float)(cnt[s0] + 1));
        float w1 = rsqrtf((float)(cnt[s1] + 1));
        sh8 r0 = *(const sh8*)&tbl[(size_t)s0 * 256 + d0];
        sh8 r1 = *(const sh8*)&tbl[(size_t)s1 * 256 + d0];
#pragma unroll
        for (int j = 0; j < 8; ++j) a[j] = fmaf(b2f((ushort)r0[j]), w0, a[j]);
#pragma unroll
        for (int j = 0; j < 8; ++j) a[j] = fmaf(b2f((ushort)r1[j]), w1, a[j]);
    }
    if (i < n) {
        int s0 = __builtin_nontemporal_load(ep + i);
        float w0 = rsqrtf((float)(cnt[s0] + 1));
        sh8 r0 = *(const sh8*)&tbl[(size_t)s0 * 256 + d0];
#pragma unroll
        for (int j = 0; j < 8; ++j) a[j] = fmaf(b2f((ushort)r0[j]), w0, a[j]);
    }

    // reduce across the 4 quarters (lanes l, l^16, l^32, l^48 own the same dims)
#pragma unroll
    for (int j = 0; j < 8; ++j) {
        a[j] += __shfl_xor(a[j], 16);
        a[j] += __shfl_xor(a[j], 32);
        a[j] *= dv;
    }

    if (qtr == 0) {
        const size_t o = (size_t)v * 256 + d0;
        if (FINAL) {
            float* out = (float*)outv;
            f32x4 p0 = __builtin_nontemporal_load((const f32x4*)&pert[o]);
            f32x4 p1 = __builtin_nontemporal_load((const f32x4*)&pert[o + 4]);
            const float4 b0 = *(const float4*)&bias[d0];
            const float4 b1 = *(const float4*)&bias[d0 + 4];
            f32x4 o0 = {a[0] + b0.x + p0.x, a[1] + b0.y + p0.y,
                        a[2] + b0.z + p0.z, a[3] + b0.w + p0.w};
            f32x4 o1 = {a[4] + b1.x + p1.x, a[5] + b1.y + p1.y,
                        a[6] + b1.z + p1.z, a[7] + b1.w + p1.w};
            __builtin_nontemporal_store(o0, (f32x4*)&out[o]);
            __builtin_nontemporal_store(o1, (f32x4*)&out[o + 4]);
        } else {
            ushort* out = (ushort*)outv;
            u16x4 o0 = {f2b(a[0]), f2b(a[1]), f2b(a[2]), f2b(a[3])};
            u16x4 o1 = {f2b(a[4]), f2b(a[5]), f2b(a[6]), f2b(a[7])};
            __builtin_nontemporal_store(o0, (u16x4*)&out[o]);
            __builtin_nontemporal_store(o1, (u16x4*)&out[o + 4]);
        }
    }
}

// bf16 MFMA GEMM: C[M,N] = A[M,K] @ Bt[N,K]^T, 64x64 tile, 4 waves (2x2), BK=64.
// Double-buffered global_load_lds with COUNTED vmcnt (T3-minimum, m218 pattern):
// stage t+1 issued before computing t; vmcnt(4) keeps next stage in flight across
// raw s_barrier (no __syncthreads drain). Both-sides XOR swizzle; XCD tile swizzle.
template <bool BIAS, int K>
__global__ __launch_bounds__(256) void k_gemm(const ushort* __restrict__ A,
                                              const ushort* __restrict__ Bt,
                                              const float* __restrict__ bias,
                                              const float* __restrict__ pert,
                                              ushort* __restrict__ C,
                                              int M, int N) {
    __shared__ ushort As[2][64][64];
    __shared__ ushort Bs[2][64][64];
    const int T = gridDim.x;
    const int q = T >> 3, r = T & 7;
    const int xcd = blockIdx.x & 7, jj = blockIdx.x >> 3;
    const int tid = (xcd < r ? xcd * (q + 1) : r * (q + 1) + (xcd - r) * q) + jj;
    const int nbx = N >> 6;
    const int bm = (tid / nbx) * 64;
    const int bn = (tid % nbx) * 64;

    const int t = threadIdx.x;
    const int lane = t & 63;
    const int w = t >> 6;
    const int wm = (w >> 1) * 32, wn = (w & 1) * 32;
    const int fr = lane & 15, kb = lane >> 4;     // kb: k 16B-chunk sub-index 0..3

    const int rho  = lane >> 3;                   // row within 8-row chunk
    const int scol = ((lane & 7) ^ rho) * 8;      // pre-swizzled source k offset
    const int c0 = w, c1 = w + 4;
    const ushort* gA0 = A  + (size_t)(bm + c0 * 8 + rho) * K + scol;
    const ushort* gA1 = A  + (size_t)(bm + c1 * 8 + rho) * K + scol;
    const ushort* gB0 = Bt + (size_t)(bn + c0 * 8 + rho) * K + scol;
    const ushort* gB1 = Bt + (size_t)(bn + c1 * 8 + rho) * K + scol;

    f32x4 acc[2][2] = {};
    constexpr int NT = K >> 6;

    // prologue: stage tile 0 into buffer 0
    g2l16(gA0, &As[0][0][0] + c0 * 512); g2l16(gA1, &As[0][0][0] + c1 * 512);
    g2l16(gB0, &Bs[0][0][0] + c0 * 512); g2l16(gB1, &Bs[0][0][0] + c1 * 512);
    gA0 += 64; gA1 += 64; gB0 += 64; gB1 += 64;

#pragma unroll
    for (int kt = 0; kt < NT; ++kt) {
        const int sel = kt & 1;
        if (kt + 1 < NT) {                  // stage next tile into the other buffer
            const int sx = sel ^ 1;
            g2l16(gA0, &As[sx][0][0] + c0 * 512); g2l16(gA1, &As[sx][0][0] + c1 * 512);
            g2l16(gB0, &Bs[sx][0][0] + c0 * 512); g2l16(gB1, &Bs[sx][0][0] + c1 * 512);
            gA0 += 64; gA1 += 64; gB0 += 64; gB1 += 64;
            asm volatile("s_waitcnt vmcnt(4)" ::: "memory");  // tile kt landed
        } else {
            asm volatile("s_waitcnt vmcnt(0)" ::: "memory");
        }
        __builtin_amdgcn_s_barrier();       // all waves' stage-kt writes visible
        __builtin_amdgcn_sched_barrier(0);
#pragma unroll
        for (int ks = 0; ks < 2; ++ks) {
            const int slot = ((ks * 4 + kb) ^ (fr & 7)) * 8;   // swizzled read
            sh8 a0 = *(const sh8*)&As[sel][wm + fr][slot];
            sh8 a1 = *(const sh8*)&As[sel][wm + 16 + fr][slot];
            sh8 b0 = *(const sh8*)&Bs[sel][wn + fr][slot];
            sh8 b1 = *(const sh8*)&Bs[sel][wn + 16 + fr][slot];
            acc[0][0] = __builtin_amdgcn_mfma_f32_16x16x32_bf16(a0, b0, acc[0][0], 0, 0, 0);
            acc[0][1] = __builtin_amdgcn_mfma_f32_16x16x32_bf16(a0, b1, acc[0][1], 0, 0, 0);
            acc[1][0] = __builtin_amdgcn_mfma_f32_16x16x32_bf16(a1, b0, acc[1][0], 0, 0, 0);
            acc[1][1] = __builtin_amdgcn_mfma_f32_16x16x32_bf16(a1, b1, acc[1][1], 0, 0, 0);
        }
        __builtin_amdgcn_sched_barrier(0);
        __builtin_amdgcn_s_barrier();       // reads of buf[sel] done before overwrite
    }

    // epilogue: row invariant in inner loop -> contiguous stores per (fm,i)
#pragma unroll
    for (int fm = 0; fm < 2; ++fm)
#pragma unroll
        for (int i = 0; i < 4; ++i) {
            int row = bm + wm + fm * 16 + (lane >> 4) * 4 + i;
            if (row < M) {
#pragma unroll
                for (int fn = 0; fn < 2; ++fn) {
                    int col = bn + wn + fn * 16 + fr;
                    float val = acc[fm][fn][i];
                    if (BIAS) val += bias[col] + pert[(size_t)row * N + col];
                    C[(size_t)row * N + col] = f2b(val);
                }
            }
        }
}

extern "C" void kernel_launch(void* const* d_in, const int* in_sizes, int n_in,
                              void* d_out, int out_size, void* d_ws, size_t ws_size,
                              hipStream_t stream) {
    const float* x  = (const float*)d_in[0];
    const int*   ei = (const int*)d_in[1];
    const float* pf = (const float*)d_in[2];
    const float* pl = (const float*)d_in[3];
    const float* W1 = (const float*)d_in[4];
    const float* b1 = (const float*)d_in[5];
    const float* W2 = (const float*)d_in[6];
    const float* b2 = (const float*)d_in[7];
    float* out = (float*)d_out;

    const int* src = ei;
    const int* dst = ei + NE;

    // workspace layout (bytes, all 16B-aligned). Adjacency matters: gemm staging
    // reads up to 47 rows past M in A-buffers (xa->W1t, hmid->h2 both valid).
    char* p = (char*)d_ws;
    int*    cursor = (int*)p;            p += 10240 * 4;     // degree counts after fill
    int*    edges  = (int*)p;            p += (size_t)NN * CAP * 4;      // 3.84 MB
    ushort* xb     = (ushort*)p;         p += (size_t)NN * IN_DIM * 2;   // bf16 x
    ushort* xa     = (ushort*)p;         p += (size_t)NN * IN_DIM * 2;   // agg(x)
    ushort* W1t    = (ushort*)p;         p += (size_t)IN_DIM * HID_DIM * 2;
    ushort* W2t    = (ushort*)p;         p += (size_t)HID_DIM * OUT_DIM * 2;
    ushort* hmid   = (ushort*)p;         p += (size_t)NN * HID_DIM * 2;  // agg(x)@W1+b1+pf
    ushort* h2     = (ushort*)p;         p += (size_t)NN * OUT_DIM * 2;  // hmid@W2

    // fused prep (xb, W1t, W2t, zero cursor) then bucket fill (cursor -> degrees)
    k_conv<<<3564, 256, 0, stream>>>(x, xb, W1, W1t, W2, W2t, cursor);
    k_fill<<<(NE + 255) / 256, 256, 0, stream>>>(src, dst, cursor, edges, NE);

    const int nby = (NN + 63) / 64;   // 157

    // layer 1: agg first (256 dims, XCD-pinned + nt streams), then GEMM -> hmid bf16
    k_agg<false><<<(NN / 4) * 2, 256, 0, stream>>>(xb, cursor, edges, nullptr, nullptr, xa);
    k_gemm<true, IN_DIM><<<(HID_DIM / 64) * nby, 256, 0, stream>>>(
        xa, W1t, b1, pf, hmid, NN, HID_DIM);

    // layer 2: GEMM first -> h2 bf16 (256 dims), then agg (+b2+perturb_last) -> out f32
    k_gemm<false, HID_DIM><<<(OUT_DIM / 64) * nby, 256, 0, stream>>>(
        hmid, W2t, nullptr, nullptr, h2, NN, OUT_DIM);
    k_agg<true><<<(NN / 4) * 2, 256, 0, stream>>>(h2, cursor, edges, b2, pl, (void*)out);
}

// Round 14
// 87.989 us; speedup vs baseline: 1.1875x; 1.1875x over previous
//
#include <hip/hip_runtime.h>
#include <hip/hip_bf16.h>

#define NN 10000
#define NE 320000
#define IN_DIM 256
#define HID_DIM 512
#define OUT_DIM 256
#define CAP 96   // per-node edge bucket capacity; P(deg>96)~1e-15 for uniform 320k/10k

typedef __attribute__((ext_vector_type(8))) short sh8;
typedef __attribute__((ext_vector_type(4))) float f32x4;
typedef __attribute__((ext_vector_type(8))) ushort u16x8;

__device__ __forceinline__ ushort f2b(float f) {
    uint u = __builtin_bit_cast(uint, f);
    u = (u + 0x7FFFu + ((u >> 16) & 1u)) >> 16;
    return (ushort)u;
}
__device__ __forceinline__ float b2f(ushort h) {
    uint u = ((uint)h) << 16;
    return __builtin_bit_cast(float, u);
}

// async global->LDS, 16B per lane. LDS dest = wave-uniform base + lane*16 (HW rule).
__device__ __forceinline__ void g2l16(const ushort* g, ushort* l) {
    __builtin_amdgcn_global_load_lds(
        (const __attribute__((address_space(1))) void*)g,
        (__attribute__((address_space(3))) void*)l,
        16, 0, 0);
}

// fused prep: [0,2500) x->bf16 (4/thread); [2500,2532) W1 transpose tiles;
// [2532,2564) W2 transpose tiles; [2564,2604) zero cursor.
// W transpose is a 64x64 LDS tile: float4-coalesced reads (vs old 4B-per-64B-line
// strided reads), [64][65] pad -> 2-way bank aliasing (free) on both phases.
__global__ void k_conv(const float* __restrict__ x, ushort* __restrict__ xb,
                       const float* __restrict__ W1, ushort* __restrict__ W1t,
                       const float* __restrict__ W2, ushort* __restrict__ W2t,
                       int* __restrict__ cursor) {
    __shared__ float ld[64][65];
    const int b = blockIdx.x, t = threadIdx.x;
    if (b < 2500) {
        size_t i = ((size_t)b * 256 + t) * 4;
        float4 f = *(const float4*)&x[i];
        *(ushort4*)&xb[i] = make_ushort4(f2b(f.x), f2b(f.y), f2b(f.z), f2b(f.w));
    } else if (b < 2564) {
        const float* W; ushort* Wt; int K, N, k0, n0;
        if (b < 2532) {
            int tt = b - 2500;
            W = W1; Wt = W1t; K = IN_DIM; N = HID_DIM;
            k0 = (tt & 3) * 64; n0 = (tt >> 2) * 64;    // 4 k-tiles x 8 n-tiles
        } else {
            int tt = b - 2532;
            W = W2; Wt = W2t; K = HID_DIM; N = OUT_DIM;
            k0 = (tt & 7) * 64; n0 = (tt >> 3) * 64;    // 8 k-tiles x 4 n-tiles
        }
        // phase 1: coalesced read of 64 rows x 64 cols; thread t: row kk, 16 cols
        const int kk = t >> 2, g = t & 3;
        const float* srcp = &W[(size_t)(k0 + kk) * N + n0 + g * 16];
        float4 f0 = *(const float4*)(srcp + 0);
        float4 f1 = *(const float4*)(srcp + 4);
        float4 f2 = *(const float4*)(srcp + 8);
        float4 f3 = *(const float4*)(srcp + 12);
        float fv[16] = {f0.x, f0.y, f0.z, f0.w, f1.x, f1.y, f1.z, f1.w,
                        f2.x, f2.y, f2.z, f2.w, f3.x, f3.y, f3.z, f3.w};
#pragma unroll
        for (int j = 0; j < 16; ++j) ld[g * 16 + j][kk] = fv[j];
        __syncthreads();
        // phase 2: thread t: output row nn (= source col), 16 k's; 2x16B stores
        const int nn = t >> 2, kc = (t & 3) * 16;
        u16x8 o0, o1;
#pragma unroll
        for (int j = 0; j < 8; ++j) {
            o0[j] = f2b(ld[nn][kc + j]);
            o1[j] = f2b(ld[nn][kc + 8 + j]);
        }
        *(u16x8*)&Wt[(size_t)(n0 + nn) * K + k0 + kc]     = o0;
        *(u16x8*)&Wt[(size_t)(n0 + nn) * K + k0 + kc + 8] = o1;
    } else {
        int idx = (b - 2564) * 256 + t;
        cursor[idx] = 0;                          // 40*256 = 10240 exactly
    }
}

// bucket fill, src index only; cursor ends up holding in-degree
__global__ void k_fill(const int* __restrict__ src, const int* __restrict__ dst,
                       int* cursor, int* __restrict__ edges, int e) {
    int i = blockIdx.x * blockDim.x + threadIdx.x;
    if (i < e) {
        int d = dst[i];
        int pos = atomicAdd(&cursor[d], 1);
        if (pos < CAP) edges[(size_t)d * CAP + pos] = src[i];
    }
}

// Pull aggregation over bf16 [NN][256] table (round-6 form — best known).
// One wave per node; half-wave owns a contiguous edge sub-range, 16B (8 dims)/lane;
// unroll x4 -> 8 independent row gathers in flight per wave.
// dinv computed on the fly: rsqrt(1 + cnt[·]).
template <bool FINAL>
__global__ __launch_bounds__(256) void k_agg(const ushort* __restrict__ tbl,
                                             const int* __restrict__ cnt,
                                             const int* __restrict__ edges,
                                             const float* __restrict__ bias,
                                             const float* __restrict__ pert,
                                             void* __restrict__ outv) {
    const int t = threadIdx.x;
    const int v = blockIdx.x * 4 + (t >> 6);
    const int lane = t & 63;
    const int half = lane >> 5;
    const int d0 = (lane & 31) * 8;          // 8 dims (16B) per lane
    const int deg = min(cnt[v], CAP);
    const float dv = rsqrtf((float)(deg + 1));
    const int m0 = (deg + 1) >> 1;           // half 0: m0 edges, half 1: deg-m0
    const int* ep = edges + (size_t)v * CAP + (half ? m0 : 0);
    const int n = half ? (deg - m0) : m0;

    float a[8];
    if (half == 0) {
        sh8 hv = *(const sh8*)&tbl[(size_t)v * 256 + d0];
#pragma unroll
        for (int j = 0; j < 8; ++j) a[j] = b2f((ushort)hv[j]) * dv;
    } else {
#pragma unroll
        for (int j = 0; j < 8; ++j) a[j] = 0.f;
    }

    int i = 0;
    for (; i + 4 <= n; i += 4) {
        int s0 = ep[i], s1 = ep[i + 1], s2 = ep[i + 2], s3 = ep[i + 3];
        float w0 = rsqrtf((float)(cnt[s0] + 1));
        float w1 = rsqrtf((float)(cnt[s1] + 1));
        float w2 = rsqrtf((float)(cnt[s2] + 1));
        float w3 = rsqrtf((float)(cnt[s3] + 1));
        sh8 r0 = *(const sh8*)&tbl[(size_t)s0 * 256 + d0];
        sh8 r1 = *(const sh8*)&tbl[(size_t)s1 * 256 + d0];
        sh8 r2 = *(const sh8*)&tbl[(size_t)s2 * 256 + d0];
        sh8 r3 = *(const sh8*)&tbl[(size_t)s3 * 256 + d0];
#pragma unroll
        for (int j = 0; j < 8; ++j) a[j] = fmaf(b2f((ushort)r0[j]), w0, a[j]);
#pragma unroll
        for (int j = 0; j < 8; ++j) a[j] = fmaf(b2f((ushort)r1[j]), w1, a[j]);
#pragma unroll
        for (int j = 0; j < 8; ++j) a[j] = fmaf(b2f((ushort)r2[j]), w2, a[j]);
#pragma unroll
        for (int j = 0; j < 8; ++j) a[j] = fmaf(b2f((ushort)r3[j]), w3, a[j]);
    }
    for (; i < n; ++i) {
        int s0 = ep[i];
        float w0 = rsqrtf((float)(cnt[s0] + 1));
        sh8 r0 = *(const sh8*)&tbl[(size_t)s0 * 256 + d0];
#pragma unroll
        for (int j = 0; j < 8; ++j) a[j] = fmaf(b2f((ushort)r0[j]), w0, a[j]);
    }

    // combine halves (lanes l, l^32 own the same dims)
#pragma unroll
    for (int j = 0; j < 8; ++j) a[j] = (a[j] + __shfl_xor(a[j], 32)) * dv;

    // half 0 writes dims d0..d0+3, half 1 writes d0+4..d0+7
    const int jb = half * 4;
    const size_t o = (size_t)v * 256 + d0 + jb;
    if (FINAL) {
        float* out = (float*)outv;
        float4 pv = *(const float4*)&pert[o];
        float4 bv = *(const float4*)&bias[d0 + jb];
        *(float4*)&out[o] = make_float4(a[jb + 0] + bv.x + pv.x, a[jb + 1] + bv.y + pv.y,
                                        a[jb + 2] + bv.z + pv.z, a[jb + 3] + bv.w + pv.w);
    } else {
        ushort* out = (ushort*)outv;
        *(ushort4*)&out[o] = make_ushort4(f2b(a[jb + 0]), f2b(a[jb + 1]),
                                          f2b(a[jb + 2]), f2b(a[jb + 3]));
    }
}

// bf16 MFMA GEMM: C[M,N] = A[M,K] @ Bt[N,K]^T, 64x64 tile, 4 waves (2x2), BK=64.
// Round-9 form (best known): global_load_lds staging, both-sides XOR swizzle,
// bijective XCD tile swizzle, __syncthreads drain (occupancy hides it at 8 blk/CU).
template <bool BIAS>
__global__ __launch_bounds__(256) void k_gemm(const ushort* __restrict__ A,
                                              const ushort* __restrict__ Bt,
                                              const float* __restrict__ bias,
                                              const float* __restrict__ pert,
                                              ushort* __restrict__ C,
                                              int M, int N, int K) {
    __shared__ ushort As[64][64];
    __shared__ ushort Bs[64][64];
    const int T = gridDim.x;
    const int q = T >> 3, r = T & 7;
    const int xcd = blockIdx.x & 7, jj = blockIdx.x >> 3;
    const int tid = (xcd < r ? xcd * (q + 1) : r * (q + 1) + (xcd - r) * q) + jj;
    const int nbx = N >> 6;
    const int bm = (tid / nbx) * 64;
    const int bn = (tid % nbx) * 64;

    const int t = threadIdx.x;
    const int lane = t & 63;
    const int w = t >> 6;
    const int wm = (w >> 1) * 32, wn = (w & 1) * 32;
    const int fr = lane & 15, kb = lane >> 4;     // kb: k 16B-chunk sub-index 0..3

    const int rho  = lane >> 3;                   // row within 8-row chunk
    const int scol = ((lane & 7) ^ rho) * 8;      // pre-swizzled source k offset
    const int c0 = w, c1 = w + 4;
    ushort* lA0 = &As[0][0] + c0 * 512;           // wave-uniform LDS bases (1KB chunks)
    ushort* lA1 = &As[0][0] + c1 * 512;
    ushort* lB0 = &Bs[0][0] + c0 * 512;
    ushort* lB1 = &Bs[0][0] + c1 * 512;
    const ushort* gA0 = A  + (size_t)(bm + c0 * 8 + rho) * K + scol;
    const ushort* gA1 = A  + (size_t)(bm + c1 * 8 + rho) * K + scol;
    const ushort* gB0 = Bt + (size_t)(bn + c0 * 8 + rho) * K + scol;
    const ushort* gB1 = Bt + (size_t)(bn + c1 * 8 + rho) * K + scol;

    f32x4 acc[2][2] = {};

    for (int k0 = 0; k0 < K; k0 += 64) {
        __syncthreads();
        g2l16(gA0, lA0); g2l16(gA1, lA1);
        g2l16(gB0, lB0); g2l16(gB1, lB1);
        gA0 += 64; gA1 += 64; gB0 += 64; gB1 += 64;
        __syncthreads();
#pragma unroll
        for (int ks = 0; ks < 2; ++ks) {
            const int slot = ((ks * 4 + kb) ^ (fr & 7)) * 8;   // swizzled read
            sh8 a0 = *(const sh8*)&As[wm + fr][slot];
            sh8 a1 = *(const sh8*)&As[wm + 16 + fr][slot];
            sh8 b0 = *(const sh8*)&Bs[wn + fr][slot];
            sh8 b1 = *(const sh8*)&Bs[wn + 16 + fr][slot];
            acc[0][0] = __builtin_amdgcn_mfma_f32_16x16x32_bf16(a0, b0, acc[0][0], 0, 0, 0);
            acc[0][1] = __builtin_amdgcn_mfma_f32_16x16x32_bf16(a0, b1, acc[0][1], 0, 0, 0);
            acc[1][0] = __builtin_amdgcn_mfma_f32_16x16x32_bf16(a1, b0, acc[1][0], 0, 0, 0);
            acc[1][1] = __builtin_amdgcn_mfma_f32_16x16x32_bf16(a1, b1, acc[1][1], 0, 0, 0);
        }
    }

    // epilogue: row invariant in inner loop -> contiguous stores per (fm,i)
#pragma unroll
    for (int fm = 0; fm < 2; ++fm)
#pragma unroll
        for (int i = 0; i < 4; ++i) {
            int row = bm + wm + fm * 16 + (lane >> 4) * 4 + i;
            if (row < M) {
#pragma unroll
                for (int fn = 0; fn < 2; ++fn) {
                    int col = bn + wn + fn * 16 + fr;
                    float val = acc[fm][fn][i];
                    if (BIAS) val += bias[col] + pert[(size_t)row * N + col];
                    C[(size_t)row * N + col] = f2b(val);
                }
            }
        }
}

extern "C" void kernel_launch(void* const* d_in, const int* in_sizes, int n_in,
                              void* d_out, int out_size, void* d_ws, size_t ws_size,
                              hipStream_t stream) {
    const float* x  = (const float*)d_in[0];
    const int*   ei = (const int*)d_in[1];
    const float* pf = (const float*)d_in[2];
    const float* pl = (const float*)d_in[3];
    const float* W1 = (const float*)d_in[4];
    const float* b1 = (const float*)d_in[5];
    const float* W2 = (const float*)d_in[6];
    const float* b2 = (const float*)d_in[7];
    float* out = (float*)d_out;

    const int* src = ei;
    const int* dst = ei + NE;

    // workspace layout (bytes, all 16B-aligned). Adjacency matters: gemm staging
    // reads up to 47 rows past M in A-buffers (xa->W1t, hmid->h2 both valid).
    char* p = (char*)d_ws;
    int*    cursor = (int*)p;            p += 10240 * 4;     // degree counts after fill
    int*    edges  = (int*)p;            p += (size_t)NN * CAP * 4;      // 3.84 MB
    ushort* xb     = (ushort*)p;         p += (size_t)NN * IN_DIM * 2;   // bf16 x
    ushort* xa     = (ushort*)p;         p += (size_t)NN * IN_DIM * 2;   // agg(x)
    ushort* W1t    = (ushort*)p;         p += (size_t)IN_DIM * HID_DIM * 2;
    ushort* W2t    = (ushort*)p;         p += (size_t)HID_DIM * OUT_DIM * 2;
    ushort* hmid   = (ushort*)p;         p += (size_t)NN * HID_DIM * 2;  // agg(x)@W1+b1+pf
    ushort* h2     = (ushort*)p;         p += (size_t)NN * OUT_DIM * 2;  // hmid@W2

    // fused prep (xb, W1t, W2t, zero cursor) then bucket fill (cursor -> degrees)
    k_conv<<<2604, 256, 0, stream>>>(x, xb, W1, W1t, W2, W2t, cursor);
    k_fill<<<(NE + 255) / 256, 256, 0, stream>>>(src, dst, cursor, edges, NE);

    const int nby = (NN + 63) / 64;   // 157

    // layer 1: agg first (256 dims), then GEMM (+b1+perturb_first) -> hmid bf16
    k_agg<false><<<NN / 4, 256, 0, stream>>>(xb, cursor, edges, nullptr, nullptr, xa);
    k_gemm<true><<<(HID_DIM / 64) * nby, 256, 0, stream>>>(
        xa, W1t, b1, pf, hmid, NN, HID_DIM, IN_DIM);

    // layer 2: GEMM first -> h2 bf16 (256 dims), then agg (+b2+perturb_last) -> out f32
    k_gemm<false><<<(OUT_DIM / 64) * nby, 256, 0, stream>>>(
        hmid, W2t, nullptr, nullptr, h2, NN, OUT_DIM, HID_DIM);
    k_agg<true><<<NN / 4, 256, 0, stream>>>(h2, cursor, edges, b2, pl, (void*)out);
}